// Round 8
// baseline (459.684 us; speedup 1.0000x reference)
//
#include <hip/hip_runtime.h>

typedef unsigned short u16;
typedef unsigned int u32;
typedef _Float16 h16;
typedef h16 v8h __attribute__((ext_vector_type(8)));
typedef float v4f __attribute__((ext_vector_type(4)));

#define ROWS_PB 16
#define TOK 48          // tokens per block, laid out tok = 16*m + r (modality-major)
#define XS 76           // sX row stride (f16 elems)
#define AS 70           // sATT row stride (f16 elems)
#define WS_L 20480      // packed f16 weight elems per layer

struct Params {
  const float *h0, *h1, *h2;
  const float *m0, *m1, *m2;
  const float *relw, *relb;
  const float *b_qkv[2], *b_o[2], *b_f[2];
  const float *n1g[2], *n1b[2], *n2g[2], *n2b[2];
  const u16* ws;
  float* out;
};

__device__ __forceinline__ u16 f2h(float f){ union{h16 h; u16 u;} c; c.h = (h16)f; return c.u; }

union Frag { uint2 u2[2]; uint4 u4; v8h v; };
union U2H  { uint2 u; h16 s[4]; };

// Pack weights as f16 fragments (A and B maps are identical):
// lane l, elem e: m/n = tile*16 + (l&15); k = kk*32 + 4*(l>>4) + (e&3) + 16*(e>>2)
__global__ __launch_bounds__(256, 2)
void prep_w(const float* wq0, const float* wo0, const float* wf0,
            const float* wq1, const float* wo1, const float* wf1, u16* ws){
  int idx = blockIdx.x * 256 + threadIdx.x;
  if (idx >= 2 * WS_L) return;
  int l = idx / WS_L, rem = idx % WS_L;
  const float* W; int loc;
  if (rem < 12288)      { W = l ? wq1 : wq0; loc = rem; }          // w_qkv (192x64)
  else if (rem < 16384) { W = l ? wo1 : wo0; loc = rem - 12288; }  // w_o (64x64)
  else                  { W = l ? wf1 : wf0; loc = rem - 16384; }  // ffn_w (64x64)
  int e = loc & 7, lane = (loc >> 3) & 63, fk = loc >> 9;
  int kk = fk & 1, nt = fk >> 1;
  int k = kk * 32 + 4 * (lane >> 4) + (e & 3) + (e >> 2) * 16;
  int n = nt * 16 + (lane & 15);
  ws[idx] = f2h(W[n * 64 + k]);
}

__device__ __forceinline__ v8h ldA(const u16* ap){
  Frag f;
  f.u2[0] = *(const uint2*)(ap);
  f.u2[1] = *(const uint2*)(ap + 16);
  return f.v;
}

__global__ __launch_bounds__(256, 5)
void inter_encoder(Params p){
  __shared__ u16  sX[TOK * XS];
  __shared__ u16  sATT[TOK * AS];
  __shared__ float sRel[TOK];

  const int tid  = threadIdx.x;
  const int lane = tid & 63, wv = tid >> 6;     // wv in 0..3 (= head for G1/attn)
  const int n15  = lane & 15, g = lane >> 4;    // g in 0..3
  const long long rowBase = (long long)blockIdx.x * ROWS_PB;

  // ---- stage X (f16): tok = 16*m + r ----
#pragma unroll
  for (int it = 0; it < 3; ++it){
    int idx = it * 256 + tid;              // 768 float4 slots = [48][16]
    int t = idx >> 4, c4 = (idx & 15) * 4;
    int m = t >> 4, r = t & 15;
    const float* hp = (m == 0) ? p.h0 : (m == 1) ? p.h1 : p.h2;
    float4 vv = *(const float4*)(hp + (rowBase + r) * 64 + c4);
    u32 lo = (u32)f2h(vv.x) | ((u32)f2h(vv.y) << 16);
    u32 hi = (u32)f2h(vv.z) | ((u32)f2h(vv.w) << 16);
    *(uint2*)(sX + t * XS + c4) = make_uint2(lo, hi);
  }
  if (tid < TOK){
    int m = tid >> 4, r = tid & 15;
    const float* mf = (m == 0) ? p.m0 : (m == 1) ? p.m1 : p.m2;
    float a0 = mf[(rowBase + r) * 2 + 0], a1 = mf[(rowBase + r) * 2 + 1];
    float z = a0 * p.relw[0] + a1 * p.relw[1] + p.relb[0];
    sRel[tid] = 1.f / (1.f + __expf(-z));
  }
  __syncthreads();

  for (int l = 0; l < 2; ++l){
    const u16* wsl = p.ws + l * WS_L;

    // ---- GEMM1^T, head-per-wave: wave wv computes Q,K,V of head wv ----
    // m-tiles {wv, 4+wv, 8+wv}; D stays in registers:
    // acc[c][m][i] = QKV[16*(4c+wv) + 4g + i][16*m + n15]  (c: 0=Q,1=K,2=V)
    Frag aq[3][2];
    v4f bq4[3];
#pragma unroll
    for (int c = 0; c < 3; ++c){
      int mt = 4 * c + wv;
      aq[c][0].u4 = *(const uint4*)(wsl + ((mt * 2 + 0) * 64 + lane) * 8);
      aq[c][1].u4 = *(const uint4*)(wsl + ((mt * 2 + 1) * 64 + lane) * 8);
      bq4[c] = *(const v4f*)(p.b_qkv[l] + 16 * mt + 4 * g);
    }
    v4f acc[3][3];
#pragma unroll
    for (int m = 0; m < 3; ++m){
      const u16* bp = sX + (16 * m + n15) * XS + 4 * g;
      v8h b0 = ldA(bp), b1 = ldA(bp + 32);
#pragma unroll
      for (int c = 0; c < 3; ++c){
        acc[c][m] = bq4[c];
        acc[c][m] = __builtin_amdgcn_mfma_f32_16x16x32_f16(aq[c][0].v, b0, acc[c][m], 0, 0, 0);
        acc[c][m] = __builtin_amdgcn_mfma_f32_16x16x32_f16(aq[c][1].v, b1, acc[c][m], 0, 0, 0);
      }
    }

    // ---- attention: fully in-register (f32). Lane owns 4 head-dims (4g+i)
    // of token r=n15 for all 3 modalities; reduce over g via shfl_xor. ----
    float s[3][3];
#pragma unroll
    for (int m1 = 0; m1 < 3; ++m1)
#pragma unroll
      for (int m2 = 0; m2 < 3; ++m2){
        float pp = acc[0][m1][0] * acc[1][m2][0]
                 + acc[0][m1][1] * acc[1][m2][1]
                 + acc[0][m1][2] * acc[1][m2][2]
                 + acc[0][m1][3] * acc[1][m2][3];
        pp += __shfl_xor(pp, 16, 64);
        pp += __shfl_xor(pp, 32, 64);
        s[m1][m2] = pp * 0.25f;
      }
#pragma unroll
    for (int m1 = 0; m1 < 3; ++m1){
      float mx = fmaxf(fmaxf(s[m1][0], s[m1][1]), s[m1][2]);
      float e0 = __expf(s[m1][0] - mx), e1 = __expf(s[m1][1] - mx), e2 = __expf(s[m1][2] - mx);
      float inv = 1.f / (e0 + e1 + e2);
      float a0 = e0 * inv, a1 = e1 * inv, a2 = e2 * inv;
      float o0 = a0 * acc[2][0][0] + a1 * acc[2][1][0] + a2 * acc[2][2][0];
      float o1 = a0 * acc[2][0][1] + a1 * acc[2][1][1] + a2 * acc[2][2][1];
      float o2 = a0 * acc[2][0][2] + a1 * acc[2][1][2] + a2 * acc[2][2][2];
      float o3 = a0 * acc[2][0][3] + a1 * acc[2][1][3] + a2 * acc[2][2][3];
      u32 lo = (u32)f2h(o0) | ((u32)f2h(o1) << 16);
      u32 hi = (u32)f2h(o2) | ((u32)f2h(o3) << 16);
      *(uint2*)(sATT + (16 * m1 + n15) * AS + 16 * wv + 4 * g) = make_uint2(lo, hi);
    }
    __syncthreads();

    // ---- chain: G2^T + LN1 + G3^T + LN2 (R7-validated); waves 0..2 ----
    if (wv < 3){
      const int trow = 16 * wv + n15;     // modality wv, row n15
      const float relt = sRel[trow];
      const u16* bp = sATT + trow * AS + 4 * g;
      v8h b0 = ldA(bp), b1 = ldA(bp + 32);

      float val[4][4];
      float psum = 0.f;
#pragma unroll
      for (int j = 0; j < 4; ++j){
        Frag a0, a1;
        a0.u4 = *(const uint4*)(wsl + 12288 + ((j * 2 + 0) * 64 + lane) * 8);
        a1.u4 = *(const uint4*)(wsl + 12288 + ((j * 2 + 1) * 64 + lane) * 8);
        v4f acc2 = *(const v4f*)(p.b_o[l] + 16 * j + 4 * g);
        acc2 = __builtin_amdgcn_mfma_f32_16x16x32_f16(a0.v, b0, acc2, 0, 0, 0);
        acc2 = __builtin_amdgcn_mfma_f32_16x16x32_f16(a1.v, b1, acc2, 0, 0, 0);
        U2H x; x.u = *(const uint2*)(sX + trow * XS + 16 * j + 4 * g);
#pragma unroll
        for (int i = 0; i < 4; ++i){
          val[j][i] = acc2[i] * relt + (float)x.s[i];
          psum += val[j][i];
        }
      }
      psum += __shfl_xor(psum, 16, 64);
      psum += __shfl_xor(psum, 32, 64);
      float mu = psum * (1.f / 64.f);
      float vs = 0.f;
#pragma unroll
      for (int j = 0; j < 4; ++j)
#pragma unroll
        for (int i = 0; i < 4; ++i){ float d = val[j][i] - mu; vs += d * d; }
      vs += __shfl_xor(vs, 16, 64);
      vs += __shfl_xor(vs, 32, 64);
      float rs = rsqrtf(vs * (1.f / 64.f) + 1e-5f);

      float y[4][4];
#pragma unroll
      for (int j = 0; j < 4; ++j){
        v4f gg = *(const v4f*)(p.n1g[l] + 16 * j + 4 * g);
        v4f bb = *(const v4f*)(p.n1b[l] + 16 * j + 4 * g);
#pragma unroll
        for (int i = 0; i < 4; ++i) y[j][i] = (val[j][i] - mu) * rs * gg[i] + bb[i];
        u32 lo = (u32)f2h(y[j][0]) | ((u32)f2h(y[j][1]) << 16);
        u32 hi = (u32)f2h(y[j][2]) | ((u32)f2h(y[j][3]) << 16);
        *(uint2*)(sX + trow * XS + 16 * j + 4 * g) = make_uint2(lo, hi);
      }

      // G3^T: B-frags read back from sX (this thread's own slice)
      const u16* ap2 = sX + trow * XS + 4 * g;
      v8h c0 = ldA(ap2), c1 = ldA(ap2 + 32);

      float psum2 = 0.f;
#pragma unroll
      for (int j = 0; j < 4; ++j){
        Frag a0, a1;
        a0.u4 = *(const uint4*)(wsl + 16384 + ((j * 2 + 0) * 64 + lane) * 8);
        a1.u4 = *(const uint4*)(wsl + 16384 + ((j * 2 + 1) * 64 + lane) * 8);
        v4f acc2 = *(const v4f*)(p.b_f[l] + 16 * j + 4 * g);
        acc2 = __builtin_amdgcn_mfma_f32_16x16x32_f16(a0.v, c0, acc2, 0, 0, 0);
        acc2 = __builtin_amdgcn_mfma_f32_16x16x32_f16(a1.v, c1, acc2, 0, 0, 0);
#pragma unroll
        for (int i = 0; i < 4; ++i){
          float v2 = y[j][i] + fmaxf(acc2[i], 0.f);
          val[j][i] = v2;
          psum2 += v2;
        }
      }
      psum2 += __shfl_xor(psum2, 16, 64);
      psum2 += __shfl_xor(psum2, 32, 64);
      float mu2 = psum2 * (1.f / 64.f);
      float vs2 = 0.f;
#pragma unroll
      for (int j = 0; j < 4; ++j)
#pragma unroll
        for (int i = 0; i < 4; ++i){ float d = val[j][i] - mu2; vs2 += d * d; }
      vs2 += __shfl_xor(vs2, 16, 64);
      vs2 += __shfl_xor(vs2, 32, 64);
      float rs2 = rsqrtf(vs2 * (1.f / 64.f) + 1e-5f);

      if (l == 0){
#pragma unroll
        for (int j = 0; j < 4; ++j){
          v4f gg = *(const v4f*)(p.n2g[0] + 16 * j + 4 * g);
          v4f bb = *(const v4f*)(p.n2b[0] + 16 * j + 4 * g);
          float z0 = (val[j][0] - mu2) * rs2 * gg[0] + bb[0];
          float z1 = (val[j][1] - mu2) * rs2 * gg[1] + bb[1];
          float z2 = (val[j][2] - mu2) * rs2 * gg[2] + bb[2];
          float z3 = (val[j][3] - mu2) * rs2 * gg[3] + bb[3];
          u32 lo = (u32)f2h(z0) | ((u32)f2h(z1) << 16);
          u32 hi = (u32)f2h(z2) | ((u32)f2h(z3) << 16);
          *(uint2*)(sX + trow * XS + 16 * j + 4 * g) = make_uint2(lo, hi);
        }
      } else {
        // out[((rowBase + r)*3 + m)*64 + feat], r = n15, m = wv
        float* op = p.out + ((rowBase + n15) * 3 + wv) * 64;
#pragma unroll
        for (int j = 0; j < 4; ++j){
          v4f gg = *(const v4f*)(p.n2g[1] + 16 * j + 4 * g);
          v4f bb = *(const v4f*)(p.n2b[1] + 16 * j + 4 * g);
          v4f yo;
#pragma unroll
          for (int i = 0; i < 4; ++i) yo[i] = (val[j][i] - mu2) * rs2 * gg[i] + bb[i];
          *(v4f*)(op + 16 * j + 4 * g) = yo;
        }
      }
    }
    __syncthreads();
  }
}

extern "C" void kernel_launch(void* const* d_in, const int* in_sizes, int n_in,
                              void* d_out, int out_size, void* d_ws, size_t ws_size,
                              hipStream_t stream){
  const float* const* in = (const float* const*)d_in;
  u16* ws = (u16*)d_ws;

  prep_w<<<(2 * WS_L + 255) / 256, 256, 0, stream>>>(
      in[8], in[10], in[12], in[18], in[20], in[22], ws);

  Params p;
  p.h0 = in[0]; p.h1 = in[1]; p.h2 = in[2];
  p.m0 = in[3]; p.m1 = in[4]; p.m2 = in[5];
  p.relw = in[6]; p.relb = in[7];
  for (int l = 0; l < 2; ++l){
    int b = 8 + 10 * l;
    p.b_qkv[l] = in[b + 1];
    p.b_o[l]   = in[b + 3];
    p.b_f[l]   = in[b + 5];
    p.n1g[l]   = in[b + 6]; p.n1b[l] = in[b + 7];
    p.n2g[l]   = in[b + 8]; p.n2b[l] = in[b + 9];
  }
  p.ws = ws;
  p.out = (float*)d_out;

  const int nblk = 524288 / ROWS_PB;  // 32768
  inter_encoder<<<nblk, 256, 0, stream>>>(p);
}

// Round 9
// 448.305 us; speedup vs baseline: 1.0254x; 1.0254x over previous
//
#include <hip/hip_runtime.h>

typedef unsigned short u16;
typedef unsigned int u32;
typedef _Float16 h16;
typedef h16 v8h __attribute__((ext_vector_type(8)));
typedef float v4f __attribute__((ext_vector_type(4)));

#define ROWS_PB 16
#define TOK 48          // tokens per block; LDS rows are m-major: row = 16*m + r
#define XS 76           // sX row stride (f16 elems)
#define AS 70           // sATT row stride (f16 elems)
#define WS_L 20480      // packed f16 weight elems per layer

struct Params {
  const float *h0, *h1, *h2;
  const float *m0, *m1, *m2;
  const float *relw, *relb;
  const float *b_qkv[2], *b_o[2], *b_f[2];
  const float *n1g[2], *n1b[2], *n2g[2], *n2b[2];
  const u16* ws;
  float* out;
};

__device__ __forceinline__ u16 f2h(float f){ union{h16 h; u16 u;} c; c.h = (h16)f; return c.u; }

union Frag { uint2 u2[2]; uint4 u4; v8h v; };
union U2H  { uint2 u; h16 s[4]; };

// Pack weights as f16 fragments (A and B maps are identical):
// lane l, elem e: m/n = tile*16 + (l&15); k = kk*32 + 4*(l>>4) + (e&3) + 16*(e>>2)
__global__ __launch_bounds__(256, 2)
void prep_w(const float* wq0, const float* wo0, const float* wf0,
            const float* wq1, const float* wo1, const float* wf1, u16* ws){
  int idx = blockIdx.x * 256 + threadIdx.x;
  if (idx >= 2 * WS_L) return;
  int l = idx / WS_L, rem = idx % WS_L;
  const float* W; int loc;
  if (rem < 12288)      { W = l ? wq1 : wq0; loc = rem; }          // w_qkv (192x64)
  else if (rem < 16384) { W = l ? wo1 : wo0; loc = rem - 12288; }  // w_o (64x64)
  else                  { W = l ? wf1 : wf0; loc = rem - 16384; }  // ffn_w (64x64)
  int e = loc & 7, lane = (loc >> 3) & 63, fk = loc >> 9;
  int kk = fk & 1, nt = fk >> 1;
  int k = kk * 32 + 4 * (lane >> 4) + (e & 3) + (e >> 2) * 16;
  int n = nt * 16 + (lane & 15);
  ws[idx] = f2h(W[n * 64 + k]);
}

__device__ __forceinline__ v8h ldA(const u16* ap){
  Frag f;
  f.u2[0] = *(const uint2*)(ap);
  f.u2[1] = *(const uint2*)(ap + 16);
  return f.v;
}

__global__ __launch_bounds__(256, 5)
void inter_encoder(Params p){
  __shared__ u16  sX[TOK * XS];
  __shared__ u16  sATT[TOK * AS];
  __shared__ float sRel[TOK];

  const int tid  = threadIdx.x;
  const int lane = tid & 63, wv = tid >> 6;     // wv in 0..3 (= head for G1/attn)
  const int n15  = lane & 15, g = lane >> 4;    // g in 0..3
  const long long rowBase = (long long)blockIdx.x * ROWS_PB;

  // ---- stage X (f16): LDS row = 16*m + r ----
#pragma unroll
  for (int it = 0; it < 3; ++it){
    int idx = it * 256 + tid;              // 768 float4 slots = [48][16]
    int t = idx >> 4, c4 = (idx & 15) * 4;
    int m = t >> 4, r = t & 15;
    const float* hp = (m == 0) ? p.h0 : (m == 1) ? p.h1 : p.h2;
    float4 vv = *(const float4*)(hp + (rowBase + r) * 64 + c4);
    u32 lo = (u32)f2h(vv.x) | ((u32)f2h(vv.y) << 16);
    u32 hi = (u32)f2h(vv.z) | ((u32)f2h(vv.w) << 16);
    *(uint2*)(sX + t * XS + c4) = make_uint2(lo, hi);
  }
  if (tid < TOK){
    int m = tid >> 4, r = tid & 15;
    const float* mf = (m == 0) ? p.m0 : (m == 1) ? p.m1 : p.m2;
    float a0 = mf[(rowBase + r) * 2 + 0], a1 = mf[(rowBase + r) * 2 + 1];
    float z = a0 * p.relw[0] + a1 * p.relw[1] + p.relb[0];
    sRel[tid] = 1.f / (1.f + __expf(-z));
  }
  __syncthreads();

  for (int l = 0; l < 2; ++l){
    const u16* wsl = p.ws + l * WS_L;

    // ---- GEMM1^T, head-per-wave: wave wv computes Q,K,V of head wv ----
    // acc[c][m][i] = QKV[16*(4c+wv) + 4g + i][16*m + n15]  (c: 0=Q,1=K,2=V)
    Frag aq[3][2];
    v4f bq4[3];
#pragma unroll
    for (int c = 0; c < 3; ++c){
      int mt = 4 * c + wv;
      aq[c][0].u4 = *(const uint4*)(wsl + ((mt * 2 + 0) * 64 + lane) * 8);
      aq[c][1].u4 = *(const uint4*)(wsl + ((mt * 2 + 1) * 64 + lane) * 8);
      bq4[c] = *(const v4f*)(p.b_qkv[l] + 16 * mt + 4 * g);
    }
    v4f acc[3][3];
#pragma unroll
    for (int m = 0; m < 3; ++m){
      const u16* bp = sX + (16 * m + n15) * XS + 4 * g;
      v8h b0 = ldA(bp), b1 = ldA(bp + 32);
#pragma unroll
      for (int c = 0; c < 3; ++c){
        acc[c][m] = bq4[c];
        acc[c][m] = __builtin_amdgcn_mfma_f32_16x16x32_f16(aq[c][0].v, b0, acc[c][m], 0, 0, 0);
        acc[c][m] = __builtin_amdgcn_mfma_f32_16x16x32_f16(aq[c][1].v, b1, acc[c][m], 0, 0, 0);
      }
    }

    // ---- attention: fully in-register (f32) ----
    float s[3][3];
#pragma unroll
    for (int m1 = 0; m1 < 3; ++m1)
#pragma unroll
      for (int m2 = 0; m2 < 3; ++m2){
        float pp = acc[0][m1][0] * acc[1][m2][0]
                 + acc[0][m1][1] * acc[1][m2][1]
                 + acc[0][m1][2] * acc[1][m2][2]
                 + acc[0][m1][3] * acc[1][m2][3];
        pp += __shfl_xor(pp, 16, 64);
        pp += __shfl_xor(pp, 32, 64);
        s[m1][m2] = pp * 0.25f;
      }
#pragma unroll
    for (int m1 = 0; m1 < 3; ++m1){
      float mx = fmaxf(fmaxf(s[m1][0], s[m1][1]), s[m1][2]);
      float e0 = __expf(s[m1][0] - mx), e1 = __expf(s[m1][1] - mx), e2 = __expf(s[m1][2] - mx);
      float inv = 1.f / (e0 + e1 + e2);
      float a0 = e0 * inv, a1 = e1 * inv, a2 = e2 * inv;
      float o0 = a0 * acc[2][0][0] + a1 * acc[2][1][0] + a2 * acc[2][2][0];
      float o1 = a0 * acc[2][0][1] + a1 * acc[2][1][1] + a2 * acc[2][2][1];
      float o2 = a0 * acc[2][0][2] + a1 * acc[2][1][2] + a2 * acc[2][2][2];
      float o3 = a0 * acc[2][0][3] + a1 * acc[2][1][3] + a2 * acc[2][2][3];
      u32 lo = (u32)f2h(o0) | ((u32)f2h(o1) << 16);
      u32 hi = (u32)f2h(o2) | ((u32)f2h(o3) << 16);
      *(uint2*)(sATT + (16 * m1 + n15) * AS + 16 * wv + 4 * g) = make_uint2(lo, hi);
    }
    __syncthreads();

    // ---- chain: G2^T + LN1 + G3^T + LN2 on waves 0..2 ----
    // chain token c = 16wv + n15 is the GLOBAL token order (out-contiguous);
    // LDS row = 16*(c%3) + c/3 (m-major).
    if (wv < 3){
      const int c = 16 * wv + n15;
      const int r = (c * 171) >> 9;        // c/3 for c<512
      const int m = c - 3 * r;
      const int row = 16 * m + r;
      const float relt = sRel[row];
      const u16* bp = sATT + row * AS + 4 * g;
      v8h b0 = ldA(bp), b1 = ldA(bp + 32);

      float val[4][4];
      float psum = 0.f;
#pragma unroll
      for (int j = 0; j < 4; ++j){
        Frag a0, a1;
        a0.u4 = *(const uint4*)(wsl + 12288 + ((j * 2 + 0) * 64 + lane) * 8);
        a1.u4 = *(const uint4*)(wsl + 12288 + ((j * 2 + 1) * 64 + lane) * 8);
        v4f acc2 = *(const v4f*)(p.b_o[l] + 16 * j + 4 * g);
        acc2 = __builtin_amdgcn_mfma_f32_16x16x32_f16(a0.v, b0, acc2, 0, 0, 0);
        acc2 = __builtin_amdgcn_mfma_f32_16x16x32_f16(a1.v, b1, acc2, 0, 0, 0);
        U2H x; x.u = *(const uint2*)(sX + row * XS + 16 * j + 4 * g);
#pragma unroll
        for (int i = 0; i < 4; ++i){
          val[j][i] = acc2[i] * relt + (float)x.s[i];
          psum += val[j][i];
        }
      }
      psum += __shfl_xor(psum, 16, 64);
      psum += __shfl_xor(psum, 32, 64);
      float mu = psum * (1.f / 64.f);
      float vs = 0.f;
#pragma unroll
      for (int j = 0; j < 4; ++j)
#pragma unroll
        for (int i = 0; i < 4; ++i){ float d = val[j][i] - mu; vs += d * d; }
      vs += __shfl_xor(vs, 16, 64);
      vs += __shfl_xor(vs, 32, 64);
      float rs = rsqrtf(vs * (1.f / 64.f) + 1e-5f);

      float y[4][4];
#pragma unroll
      for (int j = 0; j < 4; ++j){
        v4f gg = *(const v4f*)(p.n1g[l] + 16 * j + 4 * g);
        v4f bb = *(const v4f*)(p.n1b[l] + 16 * j + 4 * g);
#pragma unroll
        for (int i = 0; i < 4; ++i) y[j][i] = (val[j][i] - mu) * rs * gg[i] + bb[i];
      }

      // G3^T B-frags built IN REGISTERS from y (no LDS round trip):
      // frag elem e = y[e>>2][e&3]  (c0: j=0,1; c1: j=2,3)
      Frag c0, c1;
      c0.u4 = make_uint4((u32)f2h(y[0][0]) | ((u32)f2h(y[0][1]) << 16),
                         (u32)f2h(y[0][2]) | ((u32)f2h(y[0][3]) << 16),
                         (u32)f2h(y[1][0]) | ((u32)f2h(y[1][1]) << 16),
                         (u32)f2h(y[1][2]) | ((u32)f2h(y[1][3]) << 16));
      c1.u4 = make_uint4((u32)f2h(y[2][0]) | ((u32)f2h(y[2][1]) << 16),
                         (u32)f2h(y[2][2]) | ((u32)f2h(y[2][3]) << 16),
                         (u32)f2h(y[3][0]) | ((u32)f2h(y[3][1]) << 16),
                         (u32)f2h(y[3][2]) | ((u32)f2h(y[3][3]) << 16));

      float psum2 = 0.f;
#pragma unroll
      for (int j = 0; j < 4; ++j){
        Frag a0, a1;
        a0.u4 = *(const uint4*)(wsl + 16384 + ((j * 2 + 0) * 64 + lane) * 8);
        a1.u4 = *(const uint4*)(wsl + 16384 + ((j * 2 + 1) * 64 + lane) * 8);
        v4f acc2 = *(const v4f*)(p.b_f[l] + 16 * j + 4 * g);
        acc2 = __builtin_amdgcn_mfma_f32_16x16x32_f16(a0.v, c0.v, acc2, 0, 0, 0);
        acc2 = __builtin_amdgcn_mfma_f32_16x16x32_f16(a1.v, c1.v, acc2, 0, 0, 0);
#pragma unroll
        for (int i = 0; i < 4; ++i){
          float v2 = y[j][i] + fmaxf(acc2[i], 0.f);
          val[j][i] = v2;
          psum2 += v2;
        }
      }
      psum2 += __shfl_xor(psum2, 16, 64);
      psum2 += __shfl_xor(psum2, 32, 64);
      float mu2 = psum2 * (1.f / 64.f);
      float vs2 = 0.f;
#pragma unroll
      for (int j = 0; j < 4; ++j)
#pragma unroll
        for (int i = 0; i < 4; ++i){ float d = val[j][i] - mu2; vs2 += d * d; }
      vs2 += __shfl_xor(vs2, 16, 64);
      vs2 += __shfl_xor(vs2, 32, 64);
      float rs2 = rsqrtf(vs2 * (1.f / 64.f) + 1e-5f);

      if (l == 0){
#pragma unroll
        for (int j = 0; j < 4; ++j){
          v4f gg = *(const v4f*)(p.n2g[0] + 16 * j + 4 * g);
          v4f bb = *(const v4f*)(p.n2b[0] + 16 * j + 4 * g);
          float z0 = (val[j][0] - mu2) * rs2 * gg[0] + bb[0];
          float z1 = (val[j][1] - mu2) * rs2 * gg[1] + bb[1];
          float z2 = (val[j][2] - mu2) * rs2 * gg[2] + bb[2];
          float z3 = (val[j][3] - mu2) * rs2 * gg[3] + bb[3];
          u32 lo = (u32)f2h(z0) | ((u32)f2h(z1) << 16);
          u32 hi = (u32)f2h(z2) | ((u32)f2h(z3) << 16);
          *(uint2*)(sX + row * XS + 16 * j + 4 * g) = make_uint2(lo, hi);
        }
      } else {
        // wave wv writes tokens c=16wv..16wv+15 -> 4KB contiguous per wave
        float* op = p.out + (rowBase * 3 + c) * 64;
#pragma unroll
        for (int j = 0; j < 4; ++j){
          v4f gg = *(const v4f*)(p.n2g[1] + 16 * j + 4 * g);
          v4f bb = *(const v4f*)(p.n2b[1] + 16 * j + 4 * g);
          v4f yo;
#pragma unroll
          for (int i = 0; i < 4; ++i) yo[i] = (val[j][i] - mu2) * rs2 * gg[i] + bb[i];
          *(v4f*)(op + 16 * j + 4 * g) = yo;
        }
      }
    }
    __syncthreads();
  }
}

extern "C" void kernel_launch(void* const* d_in, const int* in_sizes, int n_in,
                              void* d_out, int out_size, void* d_ws, size_t ws_size,
                              hipStream_t stream){
  const float* const* in = (const float* const*)d_in;
  u16* ws = (u16*)d_ws;

  prep_w<<<(2 * WS_L + 255) / 256, 256, 0, stream>>>(
      in[8], in[10], in[12], in[18], in[20], in[22], ws);

  Params p;
  p.h0 = in[0]; p.h1 = in[1]; p.h2 = in[2];
  p.m0 = in[3]; p.m1 = in[4]; p.m2 = in[5];
  p.relw = in[6]; p.relb = in[7];
  for (int l = 0; l < 2; ++l){
    int b = 8 + 10 * l;
    p.b_qkv[l] = in[b + 1];
    p.b_o[l]   = in[b + 3];
    p.b_f[l]   = in[b + 5];
    p.n1g[l]   = in[b + 6]; p.n1b[l] = in[b + 7];
    p.n2g[l]   = in[b + 8]; p.n2b[l] = in[b + 9];
  }
  p.ws = ws;
  p.out = (float*)d_out;

  const int nblk = 524288 / ROWS_PB;  // 32768
  inter_encoder<<<nblk, 256, 0, stream>>>(p);
}